// Round 16
// baseline (100.147 us; speedup 1.0000x reference)
//
#include <hip/hip_runtime.h>
#include <hip/hip_fp16.h>

#define OUT_UNITS 128
#define ROWS_PER_BLOCK 8   // 512 threads = 8 waves, one row per wave

typedef unsigned uvec4 __attribute__((ext_vector_type(4)));
typedef float    fvec4 __attribute__((ext_vector_type(4)));

// ---------------- Kernel 0: fused prep -------------------------------------
// job A (i < n4):  w fp32 -> fp16 into workspace (float4 -> 4 halves)
// job B (i < nnz): CSR row pointers from sorted COO rows
__global__ void prep(const float4* __restrict__ w4, uint2* __restrict__ wh, int n4,
                     const int* __restrict__ rows, int* __restrict__ row_start,
                     int nnz, int n_rows) {
    int i = blockIdx.x * blockDim.x + threadIdx.x;
    if (i < n4) {
        float4 f = w4[i];
        __half2 h01 = __floats2half2_rn(f.x, f.y);
        __half2 h23 = __floats2half2_rn(f.z, f.w);
        wh[i] = make_uint2(*(unsigned*)&h01, *(unsigned*)&h23);
    }
    if (i < nnz) {
        int cur = rows[i];
        if (i == 0) {
            for (int r = 0; r <= cur; ++r) row_start[r] = 0;
        } else {
            int prev = rows[i - 1];
            for (int r = prev + 1; r <= cur; ++r) row_start[r] = i;
        }
        if (i == nnz - 1) {
            for (int r = cur + 1; r <= n_rows; ++r) row_start[r] = nnz;
        }
    }
}

// ---------------- Kernel 1: 8 waves/block, one row per wave ------------------
// Round 14 structure (fp16 w, quarter-wave split, 2-stage pipeline, LDS
// broadcast of (c,v)) + NONTEMPORAL loads on the w-row gathers: wh is 2 MB
// vs 32 KB L1 -> ~every gather is an L1 miss, and miss-ALLOCATION serializes
// the L1 pipe. nt flag bypasses L1 allocation; w reuse is L2-served anyway.
// cols/vals/out are touched once -> also nt. (Clang ext_vector_type used:
// the nt builtins reject HIP_vector_type wrappers.)
__global__ __launch_bounds__(512, 8)
void spmm_row_wave(const float* __restrict__ vals,
                   const __half* __restrict__ wh,
                   const int* __restrict__ cols,
                   const int* __restrict__ row_start,
                   float* __restrict__ out,
                   int n_rows) {
    __shared__ int2 cvbuf[ROWS_PER_BLOCK][64];

    const int wave = __builtin_amdgcn_readfirstlane((int)(threadIdx.x >> 6));
    const int lane = threadIdx.x & 63;
    const int r    = blockIdx.x * ROWS_PER_BLOCK + wave;
    if (r >= n_rows) return;

    const int start   = row_start[r];
    const int end     = row_start[r + 1];
    const int quarter = lane >> 4;   // which nnz of the quad
    const int sub     = lane & 15;   // 16 lanes x 8 halves = 128 cols
    const char* __restrict__ whb = (const char*)wh;
    const int loff = sub << 4;       // sub*16 bytes
    int2* cv = cvbuf[wave];

    fvec4 accA = {0.f, 0.f, 0.f, 0.f};  // cols sub*8 + 0..3
    fvec4 accB = {0.f, 0.f, 0.f, 0.f};  // cols sub*8 + 4..7

    for (int base = start; base < end; base += 64) {
        const int navail = min(64, end - base);
        // stage (c, v): pad lanes get (valid col, v=0)
        const int idx = base + min(lane, navail - 1);
        int   c_l = __builtin_nontemporal_load(cols + idx);
        float v_l = (lane < navail) ? __builtin_nontemporal_load(vals + idx) : 0.f;
        cv[lane] = make_int2(c_l, __float_as_int(v_l));
        // same-wave LDS: program-ordered, no barrier

        const int nquad  = (navail + 3) >> 2;
        const int nquad4 = (nquad + 3) & ~3;   // 4..16, multiple of 4

        // ---- prologue: stage A = quads [0,4) ----
        int2  pA[4];
        uvec4 qA[4];
#pragma unroll
        for (int j = 0; j < 4; ++j) pA[j] = cv[4 * j + quarter];
#pragma unroll
        for (int j = 0; j < 4; ++j)
            qA[j] = __builtin_nontemporal_load(
                (const uvec4*)(whb + (((size_t)(unsigned)pA[j].x) << 8) + loff));

        for (int t = 4; t < nquad4; t += 4) {
            // ---- issue stage B before consuming A ----
            int2  pB[4];
            uvec4 qB[4];
#pragma unroll
            for (int j = 0; j < 4; ++j) pB[j] = cv[4 * (t + j) + quarter];
#pragma unroll
            for (int j = 0; j < 4; ++j)
                qB[j] = __builtin_nontemporal_load(
                    (const uvec4*)(whb + (((size_t)(unsigned)pB[j].x) << 8) + loff));
            // ---- consume stage A (waits vmcnt(4): B stays in flight) ----
#pragma unroll
            for (int j = 0; j < 4; ++j) {
                float v = __int_as_float(pA[j].y);
                const __half2* h = (const __half2*)&qA[j];
                float2 f0 = __half22float2(h[0]);
                float2 f1 = __half22float2(h[1]);
                float2 f2 = __half22float2(h[2]);
                float2 f3 = __half22float2(h[3]);
                accA.x = fmaf(v, f0.x, accA.x); accA.y = fmaf(v, f0.y, accA.y);
                accA.z = fmaf(v, f1.x, accA.z); accA.w = fmaf(v, f1.y, accA.w);
                accB.x = fmaf(v, f2.x, accB.x); accB.y = fmaf(v, f2.y, accB.y);
                accB.z = fmaf(v, f3.x, accB.z); accB.w = fmaf(v, f3.y, accB.w);
            }
            // ---- rotate B -> A ----
#pragma unroll
            for (int j = 0; j < 4; ++j) { pA[j] = pB[j]; qA[j] = qB[j]; }
        }

        // ---- epilogue: consume final stage ----
#pragma unroll
        for (int j = 0; j < 4; ++j) {
            float v = __int_as_float(pA[j].y);
            const __half2* h = (const __half2*)&qA[j];
            float2 f0 = __half22float2(h[0]);
            float2 f1 = __half22float2(h[1]);
            float2 f2 = __half22float2(h[2]);
            float2 f3 = __half22float2(h[3]);
            accA.x = fmaf(v, f0.x, accA.x); accA.y = fmaf(v, f0.y, accA.y);
            accA.z = fmaf(v, f1.x, accA.z); accA.w = fmaf(v, f1.y, accA.w);
            accB.x = fmaf(v, f2.x, accB.x); accB.y = fmaf(v, f2.y, accB.y);
            accB.z = fmaf(v, f3.x, accB.z); accB.w = fmaf(v, f3.y, accB.w);
        }
    }

    // fold the 4 quarters (disjoint nnz subsets)
#pragma unroll
    for (int d = 16; d <= 32; d <<= 1) {
        accA.x += __shfl_xor(accA.x, d); accA.y += __shfl_xor(accA.y, d);
        accA.z += __shfl_xor(accA.z, d); accA.w += __shfl_xor(accA.w, d);
        accB.x += __shfl_xor(accB.x, d); accB.y += __shfl_xor(accB.y, d);
        accB.z += __shfl_xor(accB.z, d); accB.w += __shfl_xor(accB.w, d);
    }

    if (quarter == 0) {
        fvec4* o = (fvec4*)(out + (size_t)r * OUT_UNITS + sub * 8);
        __builtin_nontemporal_store(accA, o);
        __builtin_nontemporal_store(accB, o + 1);
    }
}

extern "C" void kernel_launch(void* const* d_in, const int* in_sizes, int n_in,
                              void* d_out, int out_size, void* d_ws, size_t ws_size,
                              hipStream_t stream) {
    const float* vals = (const float*)d_in[0];
    const float* w    = (const float*)d_in[1];
    const int*   rows = (const int*)d_in[2];
    const int*   cols = (const int*)d_in[3];
    float* out = (float*)d_out;

    const int nnz    = in_sizes[0];
    const int n_rows = out_size / OUT_UNITS;  // 16384
    const int w_n    = in_sizes[1];           // 8192*128 = 1048576
    const int n4     = w_n / 4;

    // ws layout: [0, 64KB+4) row_start ; [128KB, 128KB+2MB) w fp16
    int*    row_start = (int*)d_ws;
    __half* wh        = (__half*)((char*)d_ws + (128 << 10));

    const int prep_threads = (nnz > n4) ? nnz : n4;
    prep<<<(prep_threads + 255) / 256, 256, 0, stream>>>(
        (const float4*)w, (uint2*)wh, n4, rows, row_start, nnz, n_rows);
    spmm_row_wave<<<(n_rows + ROWS_PER_BLOCK - 1) / ROWS_PER_BLOCK, 512, 0, stream>>>(
        vals, wh, cols, row_start, out, n_rows);
}

// Round 17
// 91.861 us; speedup vs baseline: 1.0902x; 1.0902x over previous
//
#include <hip/hip_runtime.h>
#include <hip/hip_fp16.h>

#define OUT_UNITS 128
#define ROWS_PER_BLOCK 8   // 512 threads = 8 waves, one row per wave

// ---------------- Kernel 0: fused prep -------------------------------------
// job A (i < n4):  w fp32 -> fp16 into workspace (float4 -> 4 halves)
// job B (i < nnz): CSR row pointers from sorted COO rows
__global__ void prep(const float4* __restrict__ w4, uint2* __restrict__ wh, int n4,
                     const int* __restrict__ rows, int* __restrict__ row_start,
                     int nnz, int n_rows) {
    int i = blockIdx.x * blockDim.x + threadIdx.x;
    if (i < n4) {
        float4 f = w4[i];
        __half2 h01 = __floats2half2_rn(f.x, f.y);
        __half2 h23 = __floats2half2_rn(f.z, f.w);
        wh[i] = make_uint2(*(unsigned*)&h01, *(unsigned*)&h23);
    }
    if (i < nnz) {
        int cur = rows[i];
        if (i == 0) {
            for (int r = 0; r <= cur; ++r) row_start[r] = 0;
        } else {
            int prev = rows[i - 1];
            for (int r = prev + 1; r <= cur; ++r) row_start[r] = i;
        }
        if (i == nnz - 1) {
            for (int r = cur + 1; r <= n_rows; ++r) row_start[r] = nnz;
        }
    }
}

// ---------------- Kernel 1: 8 waves/block, one row per wave ------------------
// Round 14 structure (fp16 w, quarter-wave split: 16 lanes x 16B cover one
// 256B row, one dwordx4 serves 4 nnz; 2-stage pipeline keeps 8 x 1KB gathers
// in flight; LDS broadcast of (c,v) — non-convergent ds_read, the round-8
// win). Round 16 proved nt on the GATHERS loses 12.5 us (L1 hits are real);
// here nt is applied ONLY to the single-touch cols/vals streams so they
// don't evict w lines from L1. Gathers and stores stay cached.
__global__ __launch_bounds__(512, 8)
void spmm_row_wave(const float* __restrict__ vals,
                   const __half* __restrict__ wh,
                   const int* __restrict__ cols,
                   const int* __restrict__ row_start,
                   float* __restrict__ out,
                   int n_rows) {
    __shared__ int2 cvbuf[ROWS_PER_BLOCK][64];

    const int wave = __builtin_amdgcn_readfirstlane((int)(threadIdx.x >> 6));
    const int lane = threadIdx.x & 63;
    const int r    = blockIdx.x * ROWS_PER_BLOCK + wave;
    if (r >= n_rows) return;

    const int start   = row_start[r];
    const int end     = row_start[r + 1];
    const int quarter = lane >> 4;   // which nnz of the quad
    const int sub     = lane & 15;   // 16 lanes x 8 halves = 128 cols
    const char* __restrict__ whb = (const char*)wh;
    const int loff = sub << 4;       // sub*16 bytes
    int2* cv = cvbuf[wave];

    float4 accA = make_float4(0.f, 0.f, 0.f, 0.f);  // cols sub*8 + 0..3
    float4 accB = make_float4(0.f, 0.f, 0.f, 0.f);  // cols sub*8 + 4..7

    for (int base = start; base < end; base += 64) {
        const int navail = min(64, end - base);
        // stage (c, v): pad lanes get (valid col, v=0); nt: single-touch stream
        const int idx = base + min(lane, navail - 1);
        int   c_l = __builtin_nontemporal_load(cols + idx);
        float v_l = (lane < navail) ? __builtin_nontemporal_load(vals + idx) : 0.f;
        cv[lane] = make_int2(c_l, __float_as_int(v_l));
        // same-wave LDS: program-ordered, no barrier

        const int nquad  = (navail + 3) >> 2;
        const int nquad4 = (nquad + 3) & ~3;   // 4..16, multiple of 4

        // ---- prologue: stage A = quads [0,4) ----
        int2  pA[4];
        uint4 qA[4];
#pragma unroll
        for (int j = 0; j < 4; ++j) pA[j] = cv[4 * j + quarter];
#pragma unroll
        for (int j = 0; j < 4; ++j)
            qA[j] = *(const uint4*)(whb + (((size_t)(unsigned)pA[j].x) << 8) + loff);

        for (int t = 4; t < nquad4; t += 4) {
            // ---- issue stage B before consuming A ----
            int2  pB[4];
            uint4 qB[4];
#pragma unroll
            for (int j = 0; j < 4; ++j) pB[j] = cv[4 * (t + j) + quarter];
#pragma unroll
            for (int j = 0; j < 4; ++j)
                qB[j] = *(const uint4*)(whb + (((size_t)(unsigned)pB[j].x) << 8) + loff);
            // ---- consume stage A (waits vmcnt(4): B stays in flight) ----
#pragma unroll
            for (int j = 0; j < 4; ++j) {
                float v = __int_as_float(pA[j].y);
                const __half2* h = (const __half2*)&qA[j];
                float2 f0 = __half22float2(h[0]);
                float2 f1 = __half22float2(h[1]);
                float2 f2 = __half22float2(h[2]);
                float2 f3 = __half22float2(h[3]);
                accA.x = fmaf(v, f0.x, accA.x); accA.y = fmaf(v, f0.y, accA.y);
                accA.z = fmaf(v, f1.x, accA.z); accA.w = fmaf(v, f1.y, accA.w);
                accB.x = fmaf(v, f2.x, accB.x); accB.y = fmaf(v, f2.y, accB.y);
                accB.z = fmaf(v, f3.x, accB.z); accB.w = fmaf(v, f3.y, accB.w);
            }
            // ---- rotate B -> A ----
#pragma unroll
            for (int j = 0; j < 4; ++j) { pA[j] = pB[j]; qA[j] = qB[j]; }
        }

        // ---- epilogue: consume final stage ----
#pragma unroll
        for (int j = 0; j < 4; ++j) {
            float v = __int_as_float(pA[j].y);
            const __half2* h = (const __half2*)&qA[j];
            float2 f0 = __half22float2(h[0]);
            float2 f1 = __half22float2(h[1]);
            float2 f2 = __half22float2(h[2]);
            float2 f3 = __half22float2(h[3]);
            accA.x = fmaf(v, f0.x, accA.x); accA.y = fmaf(v, f0.y, accA.y);
            accA.z = fmaf(v, f1.x, accA.z); accA.w = fmaf(v, f1.y, accA.w);
            accB.x = fmaf(v, f2.x, accB.x); accB.y = fmaf(v, f2.y, accB.y);
            accB.z = fmaf(v, f3.x, accB.z); accB.w = fmaf(v, f3.y, accB.w);
        }
    }

    // fold the 4 quarters (disjoint nnz subsets)
#pragma unroll
    for (int d = 16; d <= 32; d <<= 1) {
        accA.x += __shfl_xor(accA.x, d); accA.y += __shfl_xor(accA.y, d);
        accA.z += __shfl_xor(accA.z, d); accA.w += __shfl_xor(accA.w, d);
        accB.x += __shfl_xor(accB.x, d); accB.y += __shfl_xor(accB.y, d);
        accB.z += __shfl_xor(accB.z, d); accB.w += __shfl_xor(accB.w, d);
    }

    if (quarter == 0) {
        float4* o = (float4*)(out + (size_t)r * OUT_UNITS + sub * 8);
        o[0] = accA;
        o[1] = accB;
    }
}

extern "C" void kernel_launch(void* const* d_in, const int* in_sizes, int n_in,
                              void* d_out, int out_size, void* d_ws, size_t ws_size,
                              hipStream_t stream) {
    const float* vals = (const float*)d_in[0];
    const float* w    = (const float*)d_in[1];
    const int*   rows = (const int*)d_in[2];
    const int*   cols = (const int*)d_in[3];
    float* out = (float*)d_out;

    const int nnz    = in_sizes[0];
    const int n_rows = out_size / OUT_UNITS;  // 16384
    const int w_n    = in_sizes[1];           // 8192*128 = 1048576
    const int n4     = w_n / 4;

    // ws layout: [0, 64KB+4) row_start ; [128KB, 128KB+2MB) w fp16
    int*    row_start = (int*)d_ws;
    __half* wh        = (__half*)((char*)d_ws + (128 << 10));

    const int prep_threads = (nnz > n4) ? nnz : n4;
    prep<<<(prep_threads + 255) / 256, 256, 0, stream>>>(
        (const float4*)w, (uint2*)wh, n4, rows, row_start, nnz, n_rows);
    spmm_row_wave<<<(n_rows + ROWS_PER_BLOCK - 1) / ROWS_PER_BLOCK, 512, 0, stream>>>(
        vals, wh, cols, row_start, out, n_rows);
}

// Round 18
// 88.059 us; speedup vs baseline: 1.1373x; 1.0432x over previous
//
#include <hip/hip_runtime.h>
#include <hip/hip_fp16.h>

#define OUT_UNITS 128
#define ROWS_PER_BLOCK 8   // 512 threads = 8 waves, one row per wave

// ---------------- Kernel 0: fused prep -------------------------------------
// job A (i < n4):  w fp32 -> fp16 into workspace (float4 -> 4 halves)
// job B (i < nnz): CSR row pointers from sorted COO rows
__global__ void prep(const float4* __restrict__ w4, uint2* __restrict__ wh, int n4,
                     const int* __restrict__ rows, int* __restrict__ row_start,
                     int nnz, int n_rows) {
    int i = blockIdx.x * blockDim.x + threadIdx.x;
    if (i < n4) {
        float4 f = w4[i];
        __half2 h01 = __floats2half2_rn(f.x, f.y);
        __half2 h23 = __floats2half2_rn(f.z, f.w);
        wh[i] = make_uint2(*(unsigned*)&h01, *(unsigned*)&h23);
    }
    if (i < nnz) {
        int cur = rows[i];
        if (i == 0) {
            for (int r = 0; r <= cur; ++r) row_start[r] = 0;
        } else {
            int prev = rows[i - 1];
            for (int r = prev + 1; r <= cur; ++r) row_start[r] = i;
        }
        if (i == nnz - 1) {
            for (int r = cur + 1; r <= n_rows; ++r) row_start[r] = nnz;
        }
    }
}

// ---------------- Kernel 1: 8 waves/block, one row per wave ------------------
// EXACT round-14 configuration — the measured optimum across all probed axes:
//  - fp16 w (r10: bytes halved, -10%); quarter-wave split: 16 lanes x 16B
//    cover one 256B row, one dwordx4 serves 4 nnz
//  - 2-stage software pipeline: 8 x 1KB gathers in flight (r13: +2us)
//  - LDS broadcast of (c,v): non-convergent ds_read (r8 win; readlane is
//    convergent and pinned MLP to 1 in r4-7)
//  - 512-thread blocks (r14)
//  - ALL loads cached: nt on gathers cost +12.5us (r16), nt on cols/vals
//    streams cost +4.3us (r17)
__global__ __launch_bounds__(512, 8)
void spmm_row_wave(const float* __restrict__ vals,
                   const __half* __restrict__ wh,
                   const int* __restrict__ cols,
                   const int* __restrict__ row_start,
                   float* __restrict__ out,
                   int n_rows) {
    __shared__ int2 cvbuf[ROWS_PER_BLOCK][64];

    const int wave = __builtin_amdgcn_readfirstlane((int)(threadIdx.x >> 6));
    const int lane = threadIdx.x & 63;
    const int r    = blockIdx.x * ROWS_PER_BLOCK + wave;
    if (r >= n_rows) return;

    const int start   = row_start[r];
    const int end     = row_start[r + 1];
    const int quarter = lane >> 4;   // which nnz of the quad
    const int sub     = lane & 15;   // 16 lanes x 8 halves = 128 cols
    const char* __restrict__ whb = (const char*)wh;
    const int loff = sub << 4;       // sub*16 bytes
    int2* cv = cvbuf[wave];

    float4 accA = make_float4(0.f, 0.f, 0.f, 0.f);  // cols sub*8 + 0..3
    float4 accB = make_float4(0.f, 0.f, 0.f, 0.f);  // cols sub*8 + 4..7

    for (int base = start; base < end; base += 64) {
        const int navail = min(64, end - base);
        // stage (c, v): pad lanes get (valid col, v=0)
        const int idx = base + min(lane, navail - 1);
        int   c_l = cols[idx];
        float v_l = (lane < navail) ? vals[idx] : 0.f;
        cv[lane] = make_int2(c_l, __float_as_int(v_l));
        // same-wave LDS: program-ordered, no barrier

        const int nquad  = (navail + 3) >> 2;
        const int nquad4 = (nquad + 3) & ~3;   // 4..16, multiple of 4

        // ---- prologue: stage A = quads [0,4) ----
        int2  pA[4];
        uint4 qA[4];
#pragma unroll
        for (int j = 0; j < 4; ++j) pA[j] = cv[4 * j + quarter];
#pragma unroll
        for (int j = 0; j < 4; ++j)
            qA[j] = *(const uint4*)(whb + (((size_t)(unsigned)pA[j].x) << 8) + loff);

        for (int t = 4; t < nquad4; t += 4) {
            // ---- issue stage B before consuming A ----
            int2  pB[4];
            uint4 qB[4];
#pragma unroll
            for (int j = 0; j < 4; ++j) pB[j] = cv[4 * (t + j) + quarter];
#pragma unroll
            for (int j = 0; j < 4; ++j)
                qB[j] = *(const uint4*)(whb + (((size_t)(unsigned)pB[j].x) << 8) + loff);
            // ---- consume stage A (waits vmcnt(4): B stays in flight) ----
#pragma unroll
            for (int j = 0; j < 4; ++j) {
                float v = __int_as_float(pA[j].y);
                const __half2* h = (const __half2*)&qA[j];
                float2 f0 = __half22float2(h[0]);
                float2 f1 = __half22float2(h[1]);
                float2 f2 = __half22float2(h[2]);
                float2 f3 = __half22float2(h[3]);
                accA.x = fmaf(v, f0.x, accA.x); accA.y = fmaf(v, f0.y, accA.y);
                accA.z = fmaf(v, f1.x, accA.z); accA.w = fmaf(v, f1.y, accA.w);
                accB.x = fmaf(v, f2.x, accB.x); accB.y = fmaf(v, f2.y, accB.y);
                accB.z = fmaf(v, f3.x, accB.z); accB.w = fmaf(v, f3.y, accB.w);
            }
            // ---- rotate B -> A ----
#pragma unroll
            for (int j = 0; j < 4; ++j) { pA[j] = pB[j]; qA[j] = qB[j]; }
        }

        // ---- epilogue: consume final stage ----
#pragma unroll
        for (int j = 0; j < 4; ++j) {
            float v = __int_as_float(pA[j].y);
            const __half2* h = (const __half2*)&qA[j];
            float2 f0 = __half22float2(h[0]);
            float2 f1 = __half22float2(h[1]);
            float2 f2 = __half22float2(h[2]);
            float2 f3 = __half22float2(h[3]);
            accA.x = fmaf(v, f0.x, accA.x); accA.y = fmaf(v, f0.y, accA.y);
            accA.z = fmaf(v, f1.x, accA.z); accA.w = fmaf(v, f1.y, accA.w);
            accB.x = fmaf(v, f2.x, accB.x); accB.y = fmaf(v, f2.y, accB.y);
            accB.z = fmaf(v, f3.x, accB.z); accB.w = fmaf(v, f3.y, accB.w);
        }
    }

    // fold the 4 quarters (disjoint nnz subsets)
#pragma unroll
    for (int d = 16; d <= 32; d <<= 1) {
        accA.x += __shfl_xor(accA.x, d); accA.y += __shfl_xor(accA.y, d);
        accA.z += __shfl_xor(accA.z, d); accA.w += __shfl_xor(accA.w, d);
        accB.x += __shfl_xor(accB.x, d); accB.y += __shfl_xor(accB.y, d);
        accB.z += __shfl_xor(accB.z, d); accB.w += __shfl_xor(accB.w, d);
    }

    if (quarter == 0) {
        float4* o = (float4*)(out + (size_t)r * OUT_UNITS + sub * 8);
        o[0] = accA;
        o[1] = accB;
    }
}

extern "C" void kernel_launch(void* const* d_in, const int* in_sizes, int n_in,
                              void* d_out, int out_size, void* d_ws, size_t ws_size,
                              hipStream_t stream) {
    const float* vals = (const float*)d_in[0];
    const float* w    = (const float*)d_in[1];
    const int*   rows = (const int*)d_in[2];
    const int*   cols = (const int*)d_in[3];
    float* out = (float*)d_out;

    const int nnz    = in_sizes[0];
    const int n_rows = out_size / OUT_UNITS;  // 16384
    const int w_n    = in_sizes[1];           // 8192*128 = 1048576
    const int n4     = w_n / 4;

    // ws layout: [0, 64KB+4) row_start ; [128KB, 128KB+2MB) w fp16
    int*    row_start = (int*)d_ws;
    __half* wh        = (__half*)((char*)d_ws + (128 << 10));

    const int prep_threads = (nnz > n4) ? nnz : n4;
    prep<<<(prep_threads + 255) / 256, 256, 0, stream>>>(
        (const float4*)w, (uint2*)wh, n4, rows, row_start, nnz, n_rows);
    spmm_row_wave<<<(n_rows + ROWS_PER_BLOCK - 1) / ROWS_PER_BLOCK, 512, 0, stream>>>(
        vals, wh, cols, row_start, out, n_rows);
}